// Round 1
// baseline (160.553 us; speedup 1.0000x reference)
//
#include <hip/hip_runtime.h>

// WeightedKappaLoss: kappa = 1 - (N * sum(W*conf)) / sum(W_ij * ht_i * hp_j)
// where conf is the 6x6 confusion histogram of (y_true, argmax(y_pred)).
// All counts are exact integers -> compute ratio in double at the end.

#define NC 6
#define NBINS 36
#define BIN_PAD 32  // uints between bins -> 128 B, one cache line per bin

__global__ void kappa_count_kernel(const float4* __restrict__ yp4,
                                   const int2* __restrict__ yt2,
                                   const float* __restrict__ yp,
                                   const int* __restrict__ yt,
                                   unsigned int* __restrict__ gconf,
                                   int npairs, int N) {
    __shared__ unsigned int sconf[NBINS];
    const int tid = threadIdx.x;
    if (tid < NBINS) sconf[tid] = 0u;
    __syncthreads();

    const int stride = gridDim.x * blockDim.x;
    for (int i = blockIdx.x * blockDim.x + tid; i < npairs; i += stride) {
        const float4 a = yp4[3 * i];
        const float4 b = yp4[3 * i + 1];
        const float4 c = yp4[3 * i + 2];
        const int2 t = yt2[i];

        // row 0: a.x a.y a.z a.w b.x b.y  (strict > keeps first max, like argmax)
        float m = a.x; int p = 0;
        if (a.y > m) { m = a.y; p = 1; }
        if (a.z > m) { m = a.z; p = 2; }
        if (a.w > m) { m = a.w; p = 3; }
        if (b.x > m) { m = b.x; p = 4; }
        if (b.y > m) { m = b.y; p = 5; }
        atomicAdd(&sconf[t.x * NC + p], 1u);

        // row 1: b.z b.w c.x c.y c.z c.w
        m = b.z; p = 0;
        if (b.w > m) { m = b.w; p = 1; }
        if (c.x > m) { m = c.x; p = 2; }
        if (c.y > m) { m = c.y; p = 3; }
        if (c.z > m) { m = c.z; p = 4; }
        if (c.w > m) { m = c.w; p = 5; }
        atomicAdd(&sconf[t.y * NC + p], 1u);
    }

    // odd-N tail (not hit for N = 4,000,000, kept for generality)
    if ((N & 1) && blockIdx.x == 0 && tid == 0) {
        const int r = N - 1;
        float m = yp[r * NC]; int p = 0;
        #pragma unroll
        for (int j = 1; j < NC; ++j) {
            const float v = yp[r * NC + j];
            if (v > m) { m = v; p = j; }
        }
        atomicAdd(&sconf[yt[r] * NC + p], 1u);
    }

    __syncthreads();
    if (tid < NBINS) {
        const unsigned int v = sconf[tid];
        if (v) atomicAdd(&gconf[tid * BIN_PAD], v);
    }
}

__global__ void kappa_final_kernel(const unsigned int* __restrict__ gconf,
                                   float* __restrict__ out, long long N) {
    long long conf[NBINS];
    long long ht[NC], hp[NC];
    #pragma unroll
    for (int i = 0; i < NC; ++i) { ht[i] = 0; hp[i] = 0; }
    #pragma unroll
    for (int k = 0; k < NBINS; ++k) conf[k] = (long long)gconf[k * BIN_PAD];

    long long num = 0;
    #pragma unroll
    for (int i = 0; i < NC; ++i) {
        #pragma unroll
        for (int j = 0; j < NC; ++j) {
            const long long w = (long long)(i - j) * (i - j);
            const long long cij = conf[i * NC + j];
            num += w * cij;
            ht[i] += cij;
            hp[j] += cij;
        }
    }
    long long den = 0;
    #pragma unroll
    for (int i = 0; i < NC; ++i) {
        #pragma unroll
        for (int j = 0; j < NC; ++j) {
            den += (long long)(i - j) * (i - j) * ht[i] * hp[j];
        }
    }
    const double kappa = 1.0 - ((double)num * (double)N) / (double)den;
    out[0] = (float)kappa;
}

extern "C" void kernel_launch(void* const* d_in, const int* in_sizes, int n_in,
                              void* d_out, int out_size, void* d_ws, size_t ws_size,
                              hipStream_t stream) {
    const float* yp = (const float*)d_in[0];
    const int* yt = (const int*)d_in[1];   // jax demotes int64 -> int32 without x64
    const int N = in_sizes[1];
    unsigned int* gconf = (unsigned int*)d_ws;

    hipMemsetAsync(d_ws, 0, NBINS * BIN_PAD * sizeof(unsigned int), stream);

    const int npairs = N / 2;
    const int block = 256;
    const int grid = 2048;  // grid-stride; ~4 pairs/thread, 73k global atomics total
    kappa_count_kernel<<<grid, block, 0, stream>>>(
        (const float4*)yp, (const int2*)yt, yp, yt, gconf, npairs, N);
    kappa_final_kernel<<<1, 1, 0, stream>>>(gconf, (float*)d_out, (long long)N);
}